// Round 1
// baseline (17600.859 us; speedup 1.0000x reference)
//
#include <hip/hip_runtime.h>
#include <math.h>

#define THREADS 256

static inline int ceil_div(int a, int b) { return (a + b - 1) / b; }

__device__ __forceinline__ float wave_sum_all(float v) {
#pragma unroll
  for (int m = 1; m < 64; m <<= 1) v += __shfl_xor(v, m);
  return v;
}
__device__ __forceinline__ float wave_max_all(float v) {
#pragma unroll
  for (int m = 1; m < 64; m <<= 1) v = fmaxf(v, __shfl_xor(v, m));
  return v;
}

// ---------------- build helpers ----------------

__global__ __launch_bounds__(THREADS) void zero_i32(int* p, int n) {
  int i = blockIdx.x * THREADS + threadIdx.x;
  if (i < n) p[i] = 0;
}

__global__ __launch_bounds__(THREADS) void init_power(float* v, float* norm2, int n, float c) {
  int i = blockIdx.x * THREADS + threadIdx.x;
  if (i < n) v[i] = c;
  if (blockIdx.x == 0 && threadIdx.x < 64) norm2[threadIdx.x] = 0.f;
}

__global__ __launch_bounds__(THREADS) void hist_deg(const int* __restrict__ row,
                                                    const int* __restrict__ col,
                                                    int* rdeg, int* cdeg, int E) {
  int e = blockIdx.x * THREADS + threadIdx.x;
  if (e < E) {
    atomicAdd(&rdeg[row[e]], 1);
    atomicAdd(&cdeg[col[e]], 1);
  }
}

__global__ __launch_bounds__(THREADS) void scan1(const int* __restrict__ in, int* bsum, int L) {
  __shared__ int lds[THREADS];
  int idx = blockIdx.x * THREADS + threadIdx.x;
  lds[threadIdx.x] = (idx < L) ? in[idx] : 0;
  __syncthreads();
  for (int off = THREADS / 2; off > 0; off >>= 1) {
    if (threadIdx.x < off) lds[threadIdx.x] += lds[threadIdx.x + off];
    __syncthreads();
  }
  if (threadIdx.x == 0) bsum[blockIdx.x] = lds[0];
}

__global__ __launch_bounds__(THREADS) void scan2(int* bsum, int B) {
  __shared__ int lds[THREADS];
  int t = threadIdx.x;
  lds[t] = (t < B) ? bsum[t] : 0;
  __syncthreads();
  for (int off = 1; off < THREADS; off <<= 1) {
    int add = (t >= off) ? lds[t - off] : 0;
    __syncthreads();
    lds[t] += add;
    __syncthreads();
  }
  if (t < B) bsum[t] = (t == 0) ? 0 : lds[t - 1];
}

__global__ __launch_bounds__(THREADS) void scan3(int* data, const int* __restrict__ bsum, int L) {
  __shared__ int lds[THREADS];
  int t = threadIdx.x;
  int idx = blockIdx.x * THREADS + t;
  int v = (idx < L) ? data[idx] : 0;
  lds[t] = v;
  __syncthreads();
  for (int off = 1; off < THREADS; off <<= 1) {
    int add = (t >= off) ? lds[t - off] : 0;
    __syncthreads();
    lds[t] += add;
    __syncthreads();
  }
  if (idx < L) data[idx] = lds[t] - v + bsum[blockIdx.x];
}

__global__ __launch_bounds__(THREADS) void scatter_edges(
    const int* __restrict__ row, const int* __restrict__ col, const float* __restrict__ val,
    const int* __restrict__ rstart, int* rcur, int* csr_col, float* csr_val,
    const int* __restrict__ cstart, int* ccur, int* csc_row, float* csc_val, int E) {
  int e = blockIdx.x * THREADS + threadIdx.x;
  if (e < E) {
    int r = row[e], c = col[e];
    float v = val[e];
    int p = rstart[r] + atomicAdd(&rcur[r], 1);
    csr_col[p] = c;
    csr_val[p] = v;
    int q = cstart[c] + atomicAdd(&ccur[c], 1);
    csc_row[q] = r;
    csc_val[q] = v;
  }
}

// ---------------- power iteration ----------------
// vout = inv * (A @ vin); norm2[k] += ||vout||^2
__global__ __launch_bounds__(THREADS) void power_spmv(
    const int* __restrict__ rs, const int* __restrict__ rcol, const float* __restrict__ rval,
    const float* __restrict__ vin, float* __restrict__ vout, float* norm2, int k, int n) {
  int i = blockIdx.x * THREADS + threadIdx.x;
  float inv = (k == 1) ? 1.0f : 1.0f / (sqrtf(norm2[k - 1]) + 1e-12f);
  float w = 0.f;
  if (i < n) {
    int e0 = rs[i], e1 = rs[i + 1];
    for (int e = e0; e < e1; ++e) w += rval[e] * vin[rcol[e]];
    w *= inv;
    vout[i] = w;
  }
  float sq = w * w;
#pragma unroll
  for (int off = 32; off > 0; off >>= 1) sq += __shfl_down(sq, off);
  __shared__ float part[4];
  if ((threadIdx.x & 63) == 0) part[threadIdx.x >> 6] = sq;
  __syncthreads();
  if (threadIdx.x == 0) atomicAdd(&norm2[k], part[0] + part[1] + part[2] + part[3]);
}

// ---------------- transposes ----------------

// features [128][N] -> x [N][128]
__global__ __launch_bounds__(256) void transpose_feat(const float* __restrict__ in,
                                                      float* __restrict__ out, int n) {
  __shared__ float tile[32][33];
  int bx = blockIdx.x;  // node tile
  int by = blockIdx.y;  // feature tile (4 of them)
  int x = bx * 32 + threadIdx.x;
  for (int dy = threadIdx.y; dy < 32; dy += 8) {
    int y = by * 32 + dy;
    tile[dy][threadIdx.x] = (x < n) ? in[(size_t)y * n + x] : 0.f;
  }
  __syncthreads();
  for (int dy = threadIdx.y; dy < 32; dy += 8) {
    int node = bx * 32 + dy;
    int feat = by * 32 + threadIdx.x;
    if (node < n) out[(size_t)node * 128 + feat] = tile[threadIdx.x][dy];
  }
}

// in[rows][cols] -> out[cols][rows]  (small matrices)
__global__ __launch_bounds__(THREADS) void transpose_small(const float* __restrict__ in,
                                                           float* __restrict__ out, int rows,
                                                           int cols) {
  int idx = blockIdx.x * THREADS + threadIdx.x;
  if (idx < rows * cols) {
    int r = idx / cols, c = idx % cols;
    out[c * rows + r] = in[idx];
  }
}

// ---------------- projection (L_inf ball via row-wise L1 projection) ----------------
// one block (64 threads) per row o of W [D][D]; writes WpT [D][D] transposed.
template <int D>
__global__ __launch_bounds__(64) void project_row(const float* __restrict__ W,
                                                  float* __restrict__ WpT,
                                                  const float* __restrict__ norm2) {
  int o = blockIdx.x;
  int l = threadIdx.x;
  float rho = sqrtf(norm2[51]) + 1e-12f;
  float k = 0.9f / rho;
  float a0 = (l < D) ? W[o * D + l] : 0.f;
  float a1 = (64 + l < D) ? W[o * D + 64 + l] : 0.f;
  float ab0 = fabsf(a0), ab1 = fabsf(a1);
  float s = wave_sum_all(ab0 + ab1);
  float mx = wave_max_all(fmaxf(ab0, ab1));
  float w0 = a0, w1 = a1;
  if (s > k) {
    float lo = 0.f, hi = mx;
    for (int it = 0; it < 50; ++it) {
      float mid = 0.5f * (lo + hi);
      float g = wave_sum_all(fmaxf(ab0 - mid, 0.f) + fmaxf(ab1 - mid, 0.f));
      if (g > k) lo = mid; else hi = mid;
    }
    float theta = 0.5f * (lo + hi);
    w0 = copysignf(fmaxf(ab0 - theta, 0.f), a0);
    w1 = copysignf(fmaxf(ab1 - theta, 0.f), a1);
  }
  if (l < D) WpT[l * D + o] = w0;
  if (64 + l < D) WpT[(64 + l) * D + o] = w1;
}

// ---------------- spmm for bt (+ Z init = relu(bt)) ----------------
template <int DOUT>
__global__ __launch_bounds__(THREADS) void spmm_bt(
    const int* __restrict__ cstart, const int* __restrict__ crow, const float* __restrict__ cval,
    const float* __restrict__ X, float* __restrict__ bt, float* __restrict__ Zinit, int n) {
  int idx = blockIdx.x * THREADS + threadIdx.x;
  int node = idx / DOUT;
  int jj = idx % DOUT;
  if (node >= n) return;
  float acc = 0.f;
  int e0 = cstart[node], e1 = cstart[node + 1];
  for (int e = e0; e < e1; ++e) acc += cval[e] * X[(size_t)crow[e] * DOUT + jj];
  bt[idx] = acc;
  Zinit[idx] = fmaxf(acc, 0.f);
}

// ---------------- fused fixed-point step: Zout = relu( (A^T Zin) @ WpT + bt ) ------
template <int DOUT, int NB>
__global__ __launch_bounds__(THREADS) void fp_step(
    const int* __restrict__ cstart, const int* __restrict__ crow, const float* __restrict__ cval,
    const float* __restrict__ Zin, const float* __restrict__ WpT, const float* __restrict__ bt,
    float* __restrict__ Zout, int n) {
  constexpr int LG = THREADS / DOUT;
  constexpr int TO = DOUT / 4;
  constexpr int TN = THREADS / TO;
  constexpr int NT = NB / TN;
  __shared__ float sT[DOUT][NB + 1];
  const int node0 = blockIdx.x * NB;
  const int tid = threadIdx.x;
  // phase 1: gather S rows (transposed into LDS)
  {
    const int jj = tid % DOUT;
    const int lg = tid / DOUT;
    for (int nn = lg; nn < NB; nn += LG) {
      int node = node0 + nn;
      float acc = 0.f;
      if (node < n) {
        int e0 = cstart[node], e1 = cstart[node + 1];
        for (int e = e0; e < e1; ++e) acc += cval[e] * Zin[(size_t)crow[e] * DOUT + jj];
      }
      sT[jj][nn] = acc;
    }
  }
  __syncthreads();
  // phase 2: register-tiled GEMM  C[n][o] = sum_j S[n][j] * WpT[j][o]
  const int o4 = tid % TO, tg = tid / TO;
  const int o0 = o4 * 4;
  float acc[NT][4];
#pragma unroll
  for (int a = 0; a < NT; ++a) acc[a][0] = acc[a][1] = acc[a][2] = acc[a][3] = 0.f;
  for (int jz = 0; jz < DOUT; ++jz) {
    const float4 w4 = *(const float4*)&WpT[jz * DOUT + o0];
#pragma unroll
    for (int a = 0; a < NT; ++a) {
      float sv = sT[jz][tg * NT + a];
      acc[a][0] += sv * w4.x;
      acc[a][1] += sv * w4.y;
      acc[a][2] += sv * w4.z;
      acc[a][3] += sv * w4.w;
    }
  }
#pragma unroll
  for (int a = 0; a < NT; ++a) {
    int node = node0 + tg * NT + a;
    if (node < n) {
      const float4 b4 = *(const float4*)&bt[(size_t)node * DOUT + o0];
      float4 z;
      z.x = fmaxf(acc[a][0] + b4.x, 0.f);
      z.y = fmaxf(acc[a][1] + b4.y, 0.f);
      z.z = fmaxf(acc[a][2] + b4.z, 0.f);
      z.w = fmaxf(acc[a][3] + b4.w, 0.f);
      *(float4*)&Zout[(size_t)node * DOUT + o0] = z;
    }
  }
}

// ---------------- dense GEMM: Out = act( X @ MT + bias + Add ) ----------------
template <int DOUT, int NB>
__global__ __launch_bounds__(THREADS) void dense_gemm(
    const float* __restrict__ X, int din, const float* __restrict__ MT,
    const float* __restrict__ bias, const float* __restrict__ Add, int act,
    float* __restrict__ Out, int n) {
  constexpr int TO = DOUT / 4;
  constexpr int TN = THREADS / TO;
  constexpr int NT = NB / TN;
  __shared__ float xs[NB][129];
  const int node0 = blockIdx.x * NB;
  const int tid = threadIdx.x;
  for (int idx = tid; idx < NB * din; idx += THREADS) {
    int nn = idx / din, j = idx % din;
    int node = node0 + nn;
    xs[nn][j] = (node < n) ? X[(size_t)node * din + j] : 0.f;
  }
  __syncthreads();
  const int o4 = tid % TO, tg = tid / TO;
  const int o0 = o4 * 4;
  float acc[NT][4];
#pragma unroll
  for (int a = 0; a < NT; ++a) acc[a][0] = acc[a][1] = acc[a][2] = acc[a][3] = 0.f;
  for (int j = 0; j < din; ++j) {
    const float4 m4 = *(const float4*)&MT[j * DOUT + o0];
#pragma unroll
    for (int a = 0; a < NT; ++a) {
      float sv = xs[tg * NT + a][j];
      acc[a][0] += sv * m4.x;
      acc[a][1] += sv * m4.y;
      acc[a][2] += sv * m4.z;
      acc[a][3] += sv * m4.w;
    }
  }
#pragma unroll
  for (int a = 0; a < NT; ++a) {
    int node = node0 + tg * NT + a;
    if (node < n) {
      float4 r;
      r.x = acc[a][0]; r.y = acc[a][1]; r.z = acc[a][2]; r.w = acc[a][3];
      if (bias) {
        r.x += bias[o0]; r.y += bias[o0 + 1]; r.z += bias[o0 + 2]; r.w += bias[o0 + 3];
      }
      if (Add) {
        const float4 a4 = *(const float4*)&Add[(size_t)node * DOUT + o0];
        r.x += a4.x; r.y += a4.y; r.z += a4.z; r.w += a4.w;
      }
      if (act == 1) {  // elu
        r.x = (r.x > 0.f) ? r.x : expm1f(r.x);
        r.y = (r.y > 0.f) ? r.y : expm1f(r.y);
        r.z = (r.z > 0.f) ? r.z : expm1f(r.z);
        r.w = (r.w > 0.f) ? r.w : expm1f(r.w);
      }
      *(float4*)&Out[(size_t)node * DOUT + o0] = r;
    }
  }
}

// ---------------- host-side dispatch ----------------

static void launch_project(int dout, const float* W, float* WpT, const float* norm2,
                           hipStream_t s) {
  switch (dout) {
    case 128: project_row<128><<<128, 64, 0, s>>>(W, WpT, norm2); break;
    case 64: project_row<64><<<64, 64, 0, s>>>(W, WpT, norm2); break;
    case 32: project_row<32><<<32, 64, 0, s>>>(W, WpT, norm2); break;
    case 16: project_row<16><<<16, 64, 0, s>>>(W, WpT, norm2); break;
  }
}

static void launch_spmm_bt(int dout, const int* cs, const int* cr, const float* cv,
                           const float* X, float* bt, float* Zi, int n, hipStream_t s) {
  int g = ceil_div(n * dout, THREADS);
  switch (dout) {
    case 128: spmm_bt<128><<<g, THREADS, 0, s>>>(cs, cr, cv, X, bt, Zi, n); break;
    case 64: spmm_bt<64><<<g, THREADS, 0, s>>>(cs, cr, cv, X, bt, Zi, n); break;
    case 32: spmm_bt<32><<<g, THREADS, 0, s>>>(cs, cr, cv, X, bt, Zi, n); break;
    case 16: spmm_bt<16><<<g, THREADS, 0, s>>>(cs, cr, cv, X, bt, Zi, n); break;
  }
}

static void launch_fp_step(int dout, const int* cs, const int* cr, const float* cv,
                           const float* Zin, const float* WpT, const float* bt, float* Zout,
                           int n, hipStream_t s) {
  switch (dout) {
    case 128: fp_step<128, 32><<<ceil_div(n, 32), THREADS, 0, s>>>(cs, cr, cv, Zin, WpT, bt, Zout, n); break;
    case 64: fp_step<64, 32><<<ceil_div(n, 32), THREADS, 0, s>>>(cs, cr, cv, Zin, WpT, bt, Zout, n); break;
    case 32: fp_step<32, 32><<<ceil_div(n, 32), THREADS, 0, s>>>(cs, cr, cv, Zin, WpT, bt, Zout, n); break;
    case 16: fp_step<16, 64><<<ceil_div(n, 64), THREADS, 0, s>>>(cs, cr, cv, Zin, WpT, bt, Zout, n); break;
  }
}

static void launch_dense_gemm(int dout, const float* X, int din, const float* MT,
                              const float* bias, const float* Add, int act, float* Out, int n,
                              hipStream_t s) {
  switch (dout) {
    case 128: dense_gemm<128, 32><<<ceil_div(n, 32), THREADS, 0, s>>>(X, din, MT, bias, Add, act, Out, n); break;
    case 64: dense_gemm<64, 32><<<ceil_div(n, 32), THREADS, 0, s>>>(X, din, MT, bias, Add, act, Out, n); break;
    case 32: dense_gemm<32, 32><<<ceil_div(n, 32), THREADS, 0, s>>>(X, din, MT, bias, Add, act, Out, n); break;
    case 16: dense_gemm<16, 64><<<ceil_div(n, 64), THREADS, 0, s>>>(X, din, MT, bias, Add, act, Out, n); break;
  }
}

extern "C" void kernel_launch(void* const* d_in, const int* in_sizes, int n_in, void* d_out,
                              int out_size, void* d_ws, size_t ws_size, hipStream_t stream) {
  const float* features = (const float*)d_in[0];
  const int* row = (const int*)d_in[1];
  const int* col = (const int*)d_in[2];
  const float* val = (const float*)d_in[3];
  const int N = in_sizes[0] / 128;
  const int E = in_sizes[1];
  static const int DIN[5] = {128, 128, 64, 64, 32};
  static const int DOUT[5] = {128, 64, 64, 32, 16};

  char* base = (char*)d_ws;
  size_t off = 0;
  auto alloc = [&](size_t bytes) -> void* {
    off = (off + 255) & ~(size_t)255;
    void* p = (void*)(base + off);
    off += bytes;
    return p;
  };

  int* rstart = (int*)alloc((size_t)(N + 1) * 4);
  int* cstart = (int*)alloc((size_t)(N + 1) * 4);
  int* rcur = (int*)alloc((size_t)N * 4);
  int* ccur = (int*)alloc((size_t)N * 4);
  int* bsum = (int*)alloc(256 * 4);
  float* norm2 = (float*)alloc(64 * 4);
  float* v_a = (float*)alloc((size_t)N * 4);
  float* v_b = (float*)alloc((size_t)N * 4);
  int* csr_col = (int*)alloc((size_t)E * 4);
  float* csr_val = (float*)alloc((size_t)E * 4);
  int* csc_row = (int*)alloc((size_t)E * 4);
  float* csc_val = (float*)alloc((size_t)E * 4);
  float* WpT = (float*)alloc(16384 * 4);
  float* OmT = (float*)alloc(16384 * 4);
  float* PwT = (float*)alloc(16384 * 4);
  float* x0 = (float*)alloc((size_t)N * 128 * 4);
  float* x1 = (float*)alloc((size_t)N * 128 * 4);
  float* xom = (float*)alloc((size_t)N * 128 * 4);
  float* btb = (float*)alloc((size_t)N * 128 * 4);
  float* z_a = (float*)alloc((size_t)N * 128 * 4);
  float* z_b = (float*)alloc((size_t)N * 128 * 4);

  const int gN = ceil_div(N, THREADS);
  const int gE = ceil_div(E, THREADS);
  const int L = N + 1;
  const int B = ceil_div(L, THREADS);

  // ---- build CSR/CSC ----
  zero_i32<<<ceil_div(N + 1, THREADS), THREADS, 0, stream>>>(rstart, N + 1);
  zero_i32<<<ceil_div(N + 1, THREADS), THREADS, 0, stream>>>(cstart, N + 1);
  zero_i32<<<gN, THREADS, 0, stream>>>(rcur, N);
  zero_i32<<<gN, THREADS, 0, stream>>>(ccur, N);
  init_power<<<gN, THREADS, 0, stream>>>(v_a, norm2, N, (float)(1.0 / sqrt((double)N)));
  hist_deg<<<gE, THREADS, 0, stream>>>(row, col, rstart, cstart, E);
  scan1<<<B, THREADS, 0, stream>>>(rstart, bsum, L);
  scan2<<<1, THREADS, 0, stream>>>(bsum, B);
  scan3<<<B, THREADS, 0, stream>>>(rstart, bsum, L);
  scan1<<<B, THREADS, 0, stream>>>(cstart, bsum, L);
  scan2<<<1, THREADS, 0, stream>>>(bsum, B);
  scan3<<<B, THREADS, 0, stream>>>(cstart, bsum, L);
  scatter_edges<<<gE, THREADS, 0, stream>>>(row, col, val, rstart, rcur, csr_col, csr_val,
                                            cstart, ccur, csc_row, csc_val, E);

  // ---- x = features^T ----
  {
    dim3 grid(ceil_div(N, 32), 4);
    dim3 block(32, 8);
    transpose_feat<<<grid, block, 0, stream>>>(features, x0, N);
  }

  // ---- spectral radius: 50 power iterations + final norm (51 spmv) ----
  for (int k = 1; k <= 51; ++k) {
    const float* vin = (k & 1) ? v_a : v_b;
    float* vout = (k & 1) ? v_b : v_a;
    power_spmv<<<gN, THREADS, 0, stream>>>(rstart, csr_col, csr_val, vin, vout, norm2, k, N);
  }

  // ---- layers ----
  float* xcur = x0;
  float* xnext = x1;
  for (int i = 0; i < 5; ++i) {
    const int din = DIN[i], dout = DOUT[i];
    const float* W = (const float*)d_in[4 + 4 * i];
    const float* Om = (const float*)d_in[5 + 4 * i];
    const float* Pw = (const float*)d_in[6 + 4 * i];
    const float* Pb = (const float*)d_in[7 + 4 * i];

    transpose_small<<<ceil_div(dout * din, THREADS), THREADS, 0, stream>>>(Om, OmT, dout, din);
    transpose_small<<<ceil_div(dout * din, THREADS), THREADS, 0, stream>>>(Pw, PwT, dout, din);
    launch_project(dout, W, WpT, norm2, stream);

    // xom = x @ Om^T
    launch_dense_gemm(dout, xcur, din, OmT, nullptr, nullptr, 0, xom, N, stream);
    // bt = A^T xom ; z_a = relu(bt)   (== fixed-point iteration 1 of 15)
    launch_spmm_bt(dout, cstart, csc_row, csc_val, xom, btb, z_a, N, stream);
    // remaining 14 iterations; ends in z_a (14 is even)
    for (int s = 0; s < 14; ++s) {
      const float* zin = (s & 1) ? z_b : z_a;
      float* zout = (s & 1) ? z_a : z_b;
      launch_fp_step(dout, cstart, csc_row, csc_val, zin, WpT, btb, zout, N, stream);
    }
    // x = z + x @ Pw^T + Pb ; elu for layers 0..3; layer 4 -> d_out
    float* outp = (i < 4) ? xnext : (float*)d_out;
    launch_dense_gemm(dout, xcur, din, PwT, Pb, z_a, (i < 4) ? 1 : 0, outp, N, stream);
    float* t = xcur; xcur = xnext; xnext = t;
  }
}

// Round 2
// 9990.568 us; speedup vs baseline: 1.7617x; 1.7617x over previous
//
#include <hip/hip_runtime.h>
#include <math.h>

#define THREADS 256

static inline int ceil_div(int a, int b) { return (a + b - 1) / b; }

__device__ __forceinline__ float wave_sum_all(float v) {
#pragma unroll
  for (int m = 1; m < 64; m <<= 1) v += __shfl_xor(v, m);
  return v;
}
__device__ __forceinline__ float wave_max_all(float v) {
#pragma unroll
  for (int m = 1; m < 64; m <<= 1) v = fmaxf(v, __shfl_xor(v, m));
  return v;
}

// 4-way-unrolled sparse gather: sum_e cval[e] * Z[crow[e]*D + jj]
template <int D>
__device__ __forceinline__ float gather_row(const int* __restrict__ crow,
                                            const float* __restrict__ cval,
                                            const float* __restrict__ Z, int e0, int e1,
                                            int jj) {
  float acc0 = 0.f, acc1 = 0.f, acc2 = 0.f, acc3 = 0.f;
  int e = e0;
  for (; e + 4 <= e1; e += 4) {
    int r0 = crow[e], r1 = crow[e + 1], r2 = crow[e + 2], r3 = crow[e + 3];
    float v0 = cval[e], v1 = cval[e + 1], v2 = cval[e + 2], v3 = cval[e + 3];
    float z0 = Z[(size_t)r0 * D + jj];
    float z1 = Z[(size_t)r1 * D + jj];
    float z2 = Z[(size_t)r2 * D + jj];
    float z3 = Z[(size_t)r3 * D + jj];
    acc0 += v0 * z0;
    acc1 += v1 * z1;
    acc2 += v2 * z2;
    acc3 += v3 * z3;
  }
  for (; e < e1; ++e) acc0 += cval[e] * Z[(size_t)crow[e] * D + jj];
  return (acc0 + acc1) + (acc2 + acc3);
}

// ---------------- build helpers ----------------

__global__ __launch_bounds__(THREADS) void zero_i32(int* p, int n) {
  int i = blockIdx.x * THREADS + threadIdx.x;
  if (i < n) p[i] = 0;
}

__global__ __launch_bounds__(THREADS) void init_power(float* v, float* norm2, int n, float c) {
  int i = blockIdx.x * THREADS + threadIdx.x;
  if (i < n) v[i] = c;
  if (blockIdx.x == 0 && threadIdx.x < 64) norm2[threadIdx.x] = 0.f;
}

__global__ __launch_bounds__(THREADS) void hist_deg(const int* __restrict__ row,
                                                    const int* __restrict__ col,
                                                    int* rdeg, int* cdeg, int E) {
  int e = blockIdx.x * THREADS + threadIdx.x;
  if (e < E) {
    atomicAdd(&rdeg[row[e]], 1);
    atomicAdd(&cdeg[col[e]], 1);
  }
}

__global__ __launch_bounds__(THREADS) void scan1(const int* __restrict__ in, int* bsum, int L) {
  __shared__ int lds[THREADS];
  int idx = blockIdx.x * THREADS + threadIdx.x;
  lds[threadIdx.x] = (idx < L) ? in[idx] : 0;
  __syncthreads();
  for (int off = THREADS / 2; off > 0; off >>= 1) {
    if (threadIdx.x < off) lds[threadIdx.x] += lds[threadIdx.x + off];
    __syncthreads();
  }
  if (threadIdx.x == 0) bsum[blockIdx.x] = lds[0];
}

__global__ __launch_bounds__(THREADS) void scan2(int* bsum, int B) {
  __shared__ int lds[THREADS];
  int t = threadIdx.x;
  lds[t] = (t < B) ? bsum[t] : 0;
  __syncthreads();
  for (int off = 1; off < THREADS; off <<= 1) {
    int add = (t >= off) ? lds[t - off] : 0;
    __syncthreads();
    lds[t] += add;
    __syncthreads();
  }
  if (t < B) bsum[t] = (t == 0) ? 0 : lds[t - 1];
}

__global__ __launch_bounds__(THREADS) void scan3(int* data, const int* __restrict__ bsum, int L) {
  __shared__ int lds[THREADS];
  int t = threadIdx.x;
  int idx = blockIdx.x * THREADS + t;
  int v = (idx < L) ? data[idx] : 0;
  lds[t] = v;
  __syncthreads();
  for (int off = 1; off < THREADS; off <<= 1) {
    int add = (t >= off) ? lds[t - off] : 0;
    __syncthreads();
    lds[t] += add;
    __syncthreads();
  }
  if (idx < L) data[idx] = lds[t] - v + bsum[blockIdx.x];
}

__global__ __launch_bounds__(THREADS) void scatter_edges(
    const int* __restrict__ row, const int* __restrict__ col, const float* __restrict__ val,
    const int* __restrict__ rstart, int* rcur, int* csr_col, float* csr_val,
    const int* __restrict__ cstart, int* ccur, int* csc_row, float* csc_val, int E) {
  int e = blockIdx.x * THREADS + threadIdx.x;
  if (e < E) {
    int r = row[e], c = col[e];
    float v = val[e];
    int p = rstart[r] + atomicAdd(&rcur[r], 1);
    csr_col[p] = c;
    csr_val[p] = v;
    int q = cstart[c] + atomicAdd(&ccur[c], 1);
    csc_row[q] = r;
    csc_val[q] = v;
  }
}

// ---------------- power iteration ----------------
// vout = inv * (A @ vin); norm2[k] += ||vout||^2
__global__ __launch_bounds__(THREADS) void power_spmv(
    const int* __restrict__ rs, const int* __restrict__ rcol, const float* __restrict__ rval,
    const float* __restrict__ vin, float* __restrict__ vout, float* norm2, int k, int n) {
  int i = blockIdx.x * THREADS + threadIdx.x;
  float inv = (k == 1) ? 1.0f : 1.0f / (sqrtf(norm2[k - 1]) + 1e-12f);
  float w = 0.f;
  if (i < n) {
    int e0 = rs[i], e1 = rs[i + 1];
    w = gather_row<1>(rcol, rval, vin, e0, e1, 0);
    w *= inv;
    vout[i] = w;
  }
  float sq = w * w;
#pragma unroll
  for (int off = 32; off > 0; off >>= 1) sq += __shfl_down(sq, off);
  __shared__ float part[4];
  if ((threadIdx.x & 63) == 0) part[threadIdx.x >> 6] = sq;
  __syncthreads();
  if (threadIdx.x == 0) atomicAdd(&norm2[k], part[0] + part[1] + part[2] + part[3]);
}

// ---------------- transposes ----------------

__global__ __launch_bounds__(256) void transpose_feat(const float* __restrict__ in,
                                                      float* __restrict__ out, int n) {
  __shared__ float tile[32][33];
  int bx = blockIdx.x;
  int by = blockIdx.y;
  int x = bx * 32 + threadIdx.x;
  for (int dy = threadIdx.y; dy < 32; dy += 8) {
    int y = by * 32 + dy;
    tile[dy][threadIdx.x] = (x < n) ? in[(size_t)y * n + x] : 0.f;
  }
  __syncthreads();
  for (int dy = threadIdx.y; dy < 32; dy += 8) {
    int node = bx * 32 + dy;
    int feat = by * 32 + threadIdx.x;
    if (node < n) out[(size_t)node * 128 + feat] = tile[threadIdx.x][dy];
  }
}

__global__ __launch_bounds__(THREADS) void transpose_small(const float* __restrict__ in,
                                                           float* __restrict__ out, int rows,
                                                           int cols) {
  int idx = blockIdx.x * THREADS + threadIdx.x;
  if (idx < rows * cols) {
    int r = idx / cols, c = idx % cols;
    out[c * rows + r] = in[idx];
  }
}

// ---------------- projection (row-wise L1 projection via bisection) ----------------
template <int D>
__global__ __launch_bounds__(64) void project_row(const float* __restrict__ W,
                                                  float* __restrict__ WpT,
                                                  const float* __restrict__ norm2) {
  int o = blockIdx.x;
  int l = threadIdx.x;
  float rho = sqrtf(norm2[51]) + 1e-12f;
  float k = 0.9f / rho;
  float a0 = (l < D) ? W[o * D + l] : 0.f;
  float a1 = (64 + l < D) ? W[o * D + 64 + l] : 0.f;
  float ab0 = fabsf(a0), ab1 = fabsf(a1);
  float s = wave_sum_all(ab0 + ab1);
  float mx = wave_max_all(fmaxf(ab0, ab1));
  float w0 = a0, w1 = a1;
  if (s > k) {
    float lo = 0.f, hi = mx;
    for (int it = 0; it < 50; ++it) {
      float mid = 0.5f * (lo + hi);
      float g = wave_sum_all(fmaxf(ab0 - mid, 0.f) + fmaxf(ab1 - mid, 0.f));
      if (g > k) lo = mid; else hi = mid;
    }
    float theta = 0.5f * (lo + hi);
    w0 = copysignf(fmaxf(ab0 - theta, 0.f), a0);
    w1 = copysignf(fmaxf(ab1 - theta, 0.f), a1);
  }
  if (l < D) WpT[l * D + o] = w0;
  if (64 + l < D) WpT[(64 + l) * D + o] = w1;
}

// ---------------- spmm for bt (+ Z init = relu(bt)) ----------------
template <int DOUT>
__global__ __launch_bounds__(THREADS, 4) void spmm_bt(
    const int* __restrict__ cstart, const int* __restrict__ crow, const float* __restrict__ cval,
    const float* __restrict__ X, float* __restrict__ bt, float* __restrict__ Zinit, int n) {
  int idx = blockIdx.x * THREADS + threadIdx.x;
  int node = idx / DOUT;
  int jj = idx % DOUT;
  if (node >= n) return;
  int e0 = cstart[node], e1 = cstart[node + 1];
  float acc = gather_row<DOUT>(crow, cval, X, e0, e1, jj);
  bt[idx] = acc;
  Zinit[idx] = fmaxf(acc, 0.f);
}

// ---------------- fused fixed-point step: Zout = relu( (A^T Zin) @ WpT + bt ) ------
template <int DOUT, int NB>
__global__ __launch_bounds__(THREADS, 4) void fp_step(
    const int* __restrict__ cstart, const int* __restrict__ crow, const float* __restrict__ cval,
    const float* __restrict__ Zin, const float* __restrict__ WpT, const float* __restrict__ bt,
    float* __restrict__ Zout, int n) {
  constexpr int LG = THREADS / DOUT;
  constexpr int TO = DOUT / 4;
  constexpr int TN = THREADS / TO;
  constexpr int NT = NB / TN;
  __shared__ float sT[DOUT][NB + 1];
  const int node0 = blockIdx.x * NB;
  const int tid = threadIdx.x;
  // phase 1: gather S rows (transposed into LDS), 4-way MLP
  {
    const int jj = tid % DOUT;
    const int lg = tid / DOUT;
    for (int nn = lg; nn < NB; nn += LG) {
      int node = node0 + nn;
      float acc = 0.f;
      if (node < n) {
        int e0 = cstart[node], e1 = cstart[node + 1];
        acc = gather_row<DOUT>(crow, cval, Zin, e0, e1, jj);
      }
      sT[jj][nn] = acc;
    }
  }
  __syncthreads();
  // phase 2: register-tiled GEMM  C[n][o] = sum_j S[n][j] * WpT[j][o]
  const int o4 = tid % TO, tg = tid / TO;
  const int o0 = o4 * 4;
  float acc[NT][4];
#pragma unroll
  for (int a = 0; a < NT; ++a) acc[a][0] = acc[a][1] = acc[a][2] = acc[a][3] = 0.f;
  for (int jz = 0; jz < DOUT; ++jz) {
    const float4 w4 = *(const float4*)&WpT[jz * DOUT + o0];
#pragma unroll
    for (int a = 0; a < NT; ++a) {
      float sv = sT[jz][tg * NT + a];
      acc[a][0] += sv * w4.x;
      acc[a][1] += sv * w4.y;
      acc[a][2] += sv * w4.z;
      acc[a][3] += sv * w4.w;
    }
  }
#pragma unroll
  for (int a = 0; a < NT; ++a) {
    int node = node0 + tg * NT + a;
    if (node < n) {
      const float4 b4 = *(const float4*)&bt[(size_t)node * DOUT + o0];
      float4 z;
      z.x = fmaxf(acc[a][0] + b4.x, 0.f);
      z.y = fmaxf(acc[a][1] + b4.y, 0.f);
      z.z = fmaxf(acc[a][2] + b4.z, 0.f);
      z.w = fmaxf(acc[a][3] + b4.w, 0.f);
      *(float4*)&Zout[(size_t)node * DOUT + o0] = z;
    }
  }
}

// ---------------- dense GEMM: Out = act( X @ MT + bias + Add ) ----------------
template <int DOUT, int NB>
__global__ __launch_bounds__(THREADS) void dense_gemm(
    const float* __restrict__ X, int din, const float* __restrict__ MT,
    const float* __restrict__ bias, const float* __restrict__ Add, int act,
    float* __restrict__ Out, int n) {
  constexpr int TO = DOUT / 4;
  constexpr int TN = THREADS / TO;
  constexpr int NT = NB / TN;
  __shared__ float xs[NB][129];
  const int node0 = blockIdx.x * NB;
  const int tid = threadIdx.x;
  for (int idx = tid; idx < NB * din; idx += THREADS) {
    int nn = idx / din, j = idx % din;
    int node = node0 + nn;
    xs[nn][j] = (node < n) ? X[(size_t)node * din + j] : 0.f;
  }
  __syncthreads();
  const int o4 = tid % TO, tg = tid / TO;
  const int o0 = o4 * 4;
  float acc[NT][4];
#pragma unroll
  for (int a = 0; a < NT; ++a) acc[a][0] = acc[a][1] = acc[a][2] = acc[a][3] = 0.f;
  for (int j = 0; j < din; ++j) {
    const float4 m4 = *(const float4*)&MT[j * DOUT + o0];
#pragma unroll
    for (int a = 0; a < NT; ++a) {
      float sv = xs[tg * NT + a][j];
      acc[a][0] += sv * m4.x;
      acc[a][1] += sv * m4.y;
      acc[a][2] += sv * m4.z;
      acc[a][3] += sv * m4.w;
    }
  }
#pragma unroll
  for (int a = 0; a < NT; ++a) {
    int node = node0 + tg * NT + a;
    if (node < n) {
      float4 r;
      r.x = acc[a][0]; r.y = acc[a][1]; r.z = acc[a][2]; r.w = acc[a][3];
      if (bias) {
        r.x += bias[o0]; r.y += bias[o0 + 1]; r.z += bias[o0 + 2]; r.w += bias[o0 + 3];
      }
      if (Add) {
        const float4 a4 = *(const float4*)&Add[(size_t)node * DOUT + o0];
        r.x += a4.x; r.y += a4.y; r.z += a4.z; r.w += a4.w;
      }
      if (act == 1) {
        r.x = (r.x > 0.f) ? r.x : expm1f(r.x);
        r.y = (r.y > 0.f) ? r.y : expm1f(r.y);
        r.z = (r.z > 0.f) ? r.z : expm1f(r.z);
        r.w = (r.w > 0.f) ? r.w : expm1f(r.w);
      }
      *(float4*)&Out[(size_t)node * DOUT + o0] = r;
    }
  }
}

// ---------------- host-side dispatch ----------------

static void launch_project(int dout, const float* W, float* WpT, const float* norm2,
                           hipStream_t s) {
  switch (dout) {
    case 128: project_row<128><<<128, 64, 0, s>>>(W, WpT, norm2); break;
    case 64: project_row<64><<<64, 64, 0, s>>>(W, WpT, norm2); break;
    case 32: project_row<32><<<32, 64, 0, s>>>(W, WpT, norm2); break;
    case 16: project_row<16><<<16, 64, 0, s>>>(W, WpT, norm2); break;
  }
}

static void launch_spmm_bt(int dout, const int* cs, const int* cr, const float* cv,
                           const float* X, float* bt, float* Zi, int n, hipStream_t s) {
  int g = ceil_div(n * dout, THREADS);
  switch (dout) {
    case 128: spmm_bt<128><<<g, THREADS, 0, s>>>(cs, cr, cv, X, bt, Zi, n); break;
    case 64: spmm_bt<64><<<g, THREADS, 0, s>>>(cs, cr, cv, X, bt, Zi, n); break;
    case 32: spmm_bt<32><<<g, THREADS, 0, s>>>(cs, cr, cv, X, bt, Zi, n); break;
    case 16: spmm_bt<16><<<g, THREADS, 0, s>>>(cs, cr, cv, X, bt, Zi, n); break;
  }
}

static void launch_fp_step(int dout, const int* cs, const int* cr, const float* cv,
                           const float* Zin, const float* WpT, const float* bt, float* Zout,
                           int n, hipStream_t s) {
  switch (dout) {
    case 128: fp_step<128, 32><<<ceil_div(n, 32), THREADS, 0, s>>>(cs, cr, cv, Zin, WpT, bt, Zout, n); break;
    case 64: fp_step<64, 32><<<ceil_div(n, 32), THREADS, 0, s>>>(cs, cr, cv, Zin, WpT, bt, Zout, n); break;
    case 32: fp_step<32, 32><<<ceil_div(n, 32), THREADS, 0, s>>>(cs, cr, cv, Zin, WpT, bt, Zout, n); break;
    case 16: fp_step<16, 64><<<ceil_div(n, 64), THREADS, 0, s>>>(cs, cr, cv, Zin, WpT, bt, Zout, n); break;
  }
}

static void launch_dense_gemm(int dout, const float* X, int din, const float* MT,
                              const float* bias, const float* Add, int act, float* Out, int n,
                              hipStream_t s) {
  switch (dout) {
    case 128: dense_gemm<128, 32><<<ceil_div(n, 32), THREADS, 0, s>>>(X, din, MT, bias, Add, act, Out, n); break;
    case 64: dense_gemm<64, 32><<<ceil_div(n, 32), THREADS, 0, s>>>(X, din, MT, bias, Add, act, Out, n); break;
    case 32: dense_gemm<32, 32><<<ceil_div(n, 32), THREADS, 0, s>>>(X, din, MT, bias, Add, act, Out, n); break;
    case 16: dense_gemm<16, 64><<<ceil_div(n, 64), THREADS, 0, s>>>(X, din, MT, bias, Add, act, Out, n); break;
  }
}

extern "C" void kernel_launch(void* const* d_in, const int* in_sizes, int n_in, void* d_out,
                              int out_size, void* d_ws, size_t ws_size, hipStream_t stream) {
  const float* features = (const float*)d_in[0];
  const int* row = (const int*)d_in[1];
  const int* col = (const int*)d_in[2];
  const float* val = (const float*)d_in[3];
  const int N = in_sizes[0] / 128;
  const int E = in_sizes[1];
  static const int DIN[5] = {128, 128, 64, 64, 32};
  static const int DOUT[5] = {128, 64, 64, 32, 16};

  char* base = (char*)d_ws;
  size_t off = 0;
  auto alloc = [&](size_t bytes) -> void* {
    off = (off + 255) & ~(size_t)255;
    void* p = (void*)(base + off);
    off += bytes;
    return p;
  };

  int* rstart = (int*)alloc((size_t)(N + 1) * 4);
  int* cstart = (int*)alloc((size_t)(N + 1) * 4);
  int* rcur = (int*)alloc((size_t)N * 4);
  int* ccur = (int*)alloc((size_t)N * 4);
  int* bsum = (int*)alloc(256 * 4);
  float* norm2 = (float*)alloc(64 * 4);
  float* v_a = (float*)alloc((size_t)N * 4);
  float* v_b = (float*)alloc((size_t)N * 4);
  int* csr_col = (int*)alloc((size_t)E * 4);
  float* csr_val = (float*)alloc((size_t)E * 4);
  int* csc_row = (int*)alloc((size_t)E * 4);
  float* csc_val = (float*)alloc((size_t)E * 4);
  float* WpT = (float*)alloc(16384 * 4);
  float* OmT = (float*)alloc(16384 * 4);
  float* PwT = (float*)alloc(16384 * 4);
  float* x0 = (float*)alloc((size_t)N * 128 * 4);
  float* x1 = (float*)alloc((size_t)N * 128 * 4);
  float* xom = (float*)alloc((size_t)N * 128 * 4);
  float* btb = (float*)alloc((size_t)N * 128 * 4);
  float* z_a = (float*)alloc((size_t)N * 128 * 4);
  float* z_b = (float*)alloc((size_t)N * 128 * 4);

  const int gN = ceil_div(N, THREADS);
  const int gE = ceil_div(E, THREADS);
  const int L = N + 1;
  const int B = ceil_div(L, THREADS);

  // ---- build CSR/CSC ----
  zero_i32<<<ceil_div(N + 1, THREADS), THREADS, 0, stream>>>(rstart, N + 1);
  zero_i32<<<ceil_div(N + 1, THREADS), THREADS, 0, stream>>>(cstart, N + 1);
  zero_i32<<<gN, THREADS, 0, stream>>>(rcur, N);
  zero_i32<<<gN, THREADS, 0, stream>>>(ccur, N);
  init_power<<<gN, THREADS, 0, stream>>>(v_a, norm2, N, (float)(1.0 / sqrt((double)N)));
  hist_deg<<<gE, THREADS, 0, stream>>>(row, col, rstart, cstart, E);
  scan1<<<B, THREADS, 0, stream>>>(rstart, bsum, L);
  scan2<<<1, THREADS, 0, stream>>>(bsum, B);
  scan3<<<B, THREADS, 0, stream>>>(rstart, bsum, L);
  scan1<<<B, THREADS, 0, stream>>>(cstart, bsum, L);
  scan2<<<1, THREADS, 0, stream>>>(bsum, B);
  scan3<<<B, THREADS, 0, stream>>>(cstart, bsum, L);
  scatter_edges<<<gE, THREADS, 0, stream>>>(row, col, val, rstart, rcur, csr_col, csr_val,
                                            cstart, ccur, csc_row, csc_val, E);

  // ---- x = features^T ----
  {
    dim3 grid(ceil_div(N, 32), 4);
    dim3 block(32, 8);
    transpose_feat<<<grid, block, 0, stream>>>(features, x0, N);
  }

  // ---- spectral radius: 50 power iterations + final norm (51 spmv) ----
  for (int k = 1; k <= 51; ++k) {
    const float* vin = (k & 1) ? v_a : v_b;
    float* vout = (k & 1) ? v_b : v_a;
    power_spmv<<<gN, THREADS, 0, stream>>>(rstart, csr_col, csr_val, vin, vout, norm2, k, N);
  }

  // ---- layers ----
  float* xcur = x0;
  float* xnext = x1;
  for (int i = 0; i < 5; ++i) {
    const int din = DIN[i], dout = DOUT[i];
    const float* W = (const float*)d_in[4 + 4 * i];
    const float* Om = (const float*)d_in[5 + 4 * i];
    const float* Pw = (const float*)d_in[6 + 4 * i];
    const float* Pb = (const float*)d_in[7 + 4 * i];

    transpose_small<<<ceil_div(dout * din, THREADS), THREADS, 0, stream>>>(Om, OmT, dout, din);
    transpose_small<<<ceil_div(dout * din, THREADS), THREADS, 0, stream>>>(Pw, PwT, dout, din);
    launch_project(dout, W, WpT, norm2, stream);

    // xom = x @ Om^T
    launch_dense_gemm(dout, xcur, din, OmT, nullptr, nullptr, 0, xom, N, stream);
    // bt = A^T xom ; z_a = relu(bt)   (== fixed-point iteration 1 of 15)
    launch_spmm_bt(dout, cstart, csc_row, csc_val, xom, btb, z_a, N, stream);
    // remaining 14 iterations; ends in z_a (14 is even)
    for (int s = 0; s < 14; ++s) {
      const float* zin = (s & 1) ? z_b : z_a;
      float* zout = (s & 1) ? z_a : z_b;
      launch_fp_step(dout, cstart, csc_row, csc_val, zin, WpT, btb, zout, N, stream);
    }
    // x = z + x @ Pw^T + Pb ; elu for layers 0..3; layer 4 -> d_out
    float* outp = (i < 4) ? xnext : (float*)d_out;
    launch_dense_gemm(dout, xcur, din, PwT, Pb, z_a, (i < 4) ? 1 : 0, outp, N, stream);
    float* t = xcur; xcur = xnext; xnext = t;
  }
}